// Round 7
// baseline (50.067 us; speedup 1.0000x reference)
//
#include <hip/hip_runtime.h>
#include <hip/hip_cooperative_groups.h>

namespace cg = cooperative_groups;

#define NPTS 512
#define DIM  128
#define MARGIN 0.5f
#define CNT_EPS 1e-8f
#define NBLK 256            // 2 anchors per block, 1 block per CU

__device__ __forceinline__ float dot4(float4 a, float4 b) {
    return a.x * b.x + a.y * b.y + a.z * b.z + a.w * b.w;
}

// ---------------------------------------------------------------------------
// SINGLE cooperative kernel. Grid 256 x 1024 thr (16 waves) = 1 block/CU,
// co-resident (VGPR<=128 via launch_bounds). Waves 0-7 -> anchor 2*bid,
// waves 8-15 -> anchor 2*bid+1 (same distance phase as round 6, absmax 0).
// Tail: per-block partial -> plain store, grid.sync() (runtime-managed
// barrier: one agent fence + one barrier atomic per block), then block 0
// wave 0 reduces 256 partials and writes the scalar. No finalize node.
// ---------------------------------------------------------------------------
__global__ __launch_bounds__(1024, 4)
void triplet_onepass_kernel(const float* __restrict__ x,
                            const int* __restrict__ labels,
                            float* __restrict__ psum,
                            int* __restrict__ pcnt,
                            float* __restrict__ out) {
    __shared__ float drow[2][NPTS];   // distance rows for the 2 anchors
    __shared__ float posv[2][NPTS];
    __shared__ int   lab[NPTS];
    __shared__ int   npos_sh[2];
    __shared__ float wsum[16];
    __shared__ int   wcnt[16];

    const int tid = threadIdx.x;     // 0..1023
    const int h   = tid >> 9;        // half: 0 or 1
    const int t   = tid & 511;       // index within half
    const int w8  = t >> 6;          // wave-in-half 0..7
    const int l   = tid & 63;        // lane
    const int g   = l >> 2;          // row-group 0..15 within wave
    const int c   = l & 3;           // column slot 0..3

    const int i  = 2 * blockIdx.x + h;   // this half's anchor

    if (tid < NPTS) lab[tid] = labels[tid];
    if (tid < 2)    npos_sh[tid] = 0;
    const int li = labels[i];

    // anchor row fragment in registers: columns c+4*it (it=0..7)
    const float4* xi4 = (const float4*)(x + i * DIM);
    float4 xf[8];
#pragma unroll
    for (int it = 0; it < 8; ++it) xf[it] = xi4[c + 4 * it];

    // sqi = ||xi||^2 : per-lane partial, 4-lane butterfly
    float sqi = 0.f;
#pragma unroll
    for (int it = 0; it < 8; ++it) sqi += dot4(xf[it], xf[it]);
    sqi += __shfl_xor(sqi, 1, 64);
    sqi += __shfl_xor(sqi, 2, 64);

    // distance rows: pass p covers rows p*128 + w8*16 + g (per half)
#pragma unroll 2
    for (int pass = 0; pass < 4; ++pass) {
        const int j = pass * 128 + w8 * 16 + g;
        const float4* xj4 = (const float4*)(x + j * DIM);
        float dp = 0.f, sp = 0.f;
#pragma unroll
        for (int it = 0; it < 8; ++it) {
            float4 b = xj4[c + 4 * it];
            dp += dot4(b, xf[it]);
            sp += dot4(b, b);
        }
        dp += __shfl_xor(dp, 1, 64);
        dp += __shfl_xor(dp, 2, 64);
        sp += __shfl_xor(sp, 1, 64);
        sp += __shfl_xor(sp, 2, 64);
        if (c == 0) {
            float dsq = sqi + sp - 2.f * dp;
            dsq = dsq > 0.f ? dsq : 0.f;
            // reference's zero-mask only affects exact-zero entries (the
            // diagonal), excluded by validity -> plain sqrt exact here.
            drow[h][j] = (dsq == 0.f) ? 0.f : sqrtf(dsq);
        }
    }
    __syncthreads();

    // compact positives: one thread per row per half (~8 atomics/half)
    if (lab[t] == li && t != i) {
        int p = atomicAdd(&npos_sh[h], 1);
        posv[h][p] = drow[h][t] + MARGIN;
    }
    __syncthreads();
    const int npos = npos_sh[h];

    // pair loop: this thread owns k = t within its half
    const bool  isneg = (lab[t] != li);
    const float dk    = drow[h][t];
    float lsum = 0.f;
    int   lcnt = 0;
    for (int p = 0; p < npos; ++p) {
        float v = posv[h][p] - dk;       // d_ij - d_ik + margin
        if (isneg && v > 0.f) {
            lsum += v;
            lcnt += (v > CNT_EPS) ? 1 : 0;
        }
    }

    // per-wave shuffle reduce, then 16-partial combine (both anchors summed)
#pragma unroll
    for (int off = 1; off < 64; off <<= 1) {
        lsum += __shfl_xor(lsum, off, 64);
        lcnt += __shfl_xor(lcnt, off, 64);
    }
    const int wid = tid >> 6;            // 0..15
    if (l == 0) { wsum[wid] = lsum; wcnt[wid] = lcnt; }
    __syncthreads();
    if (tid == 0) {
        float s = 0.f;
        int   cc = 0;
#pragma unroll
        for (int q = 0; q < 16; ++q) { s += wsum[q]; cc += wcnt[q]; }
        psum[blockIdx.x] = s;            // plain stores; grid.sync's fence
        pcnt[blockIdx.x] = cc;           // publishes them grid-wide
    }

    cg::this_grid().sync();              // runtime-managed grid barrier

    // block 0, wave 0: deterministic fixed-order reduce of 256 partials
    if (blockIdx.x == 0 && tid < 64) {
        float4 a  = ((const float4*)psum)[tid];
        int4   ca = ((const int4*)pcnt)[tid];
        float s  = a.x + a.y + a.z + a.w;
        int   cc = ca.x + ca.y + ca.z + ca.w;
#pragma unroll
        for (int off = 1; off < 64; off <<= 1) {
            s  += __shfl_xor(s, off, 64);
            cc += __shfl_xor(cc, off, 64);
        }
        if (tid == 0) out[0] = s / (float)cc;
    }
}

extern "C" void kernel_launch(void* const* d_in, const int* in_sizes, int n_in,
                              void* d_out, int out_size, void* d_ws, size_t ws_size,
                              hipStream_t stream) {
    const float* x      = (const float*)d_in[0];   // [512,128] fp32
    const int*   labels = (const int*)d_in[1];     // [512] int32
    float*       out    = (float*)d_out;           // scalar fp32

    float* psum = (float*)d_ws;          // 256 floats (fully overwritten)
    int*   pcnt = (int*)(psum + NBLK);   // 256 ints  (fully overwritten)

    void* args[] = { (void*)&x, (void*)&labels, (void*)&psum,
                     (void*)&pcnt, (void*)&out };
    hipLaunchCooperativeKernel((const void*)triplet_onepass_kernel,
                               dim3(NBLK), dim3(1024), args, 0, stream);
}

// Round 8
// 28.816 us; speedup vs baseline: 1.7375x; 1.7375x over previous
//
#include <hip/hip_runtime.h>

#define NPTS 512
#define DIM  128
#define MARGIN 0.5f
#define CNT_EPS 1e-8f
#define NBLK 256            // 2 anchors per block, 1 block per CU
#define RPP 128             // rows per pass
#define F4R 32              // float4 per row (128 floats)
#define F4P (RPP * F4R)     // float4 per pass slab (4096 = 64 KB)

__device__ __forceinline__ float dot4(float4 a, float4 b) {
    return a.x * b.x + a.y * b.y + a.z * b.z + a.w * b.w;
}

// ---------------------------------------------------------------------------
// One block (1024 thr = 16 waves) per 2 anchors, grid 256 = 1 block/CU.
// NEW vs r6: each 128-row pass is staged into a 64 KB LDS buffer ONCE
// (coalesced float4 loads, T14 early-issue for pass p+1 under compute of p),
// and BOTH anchor-halves consume it via swizzled ds_read_b128
// (phys_f4 = m ^ (row&7) kills the 4-lane-per-row bank conflict).
// Per-CU global traffic halves (512 -> 256 KB) and load latency pipelines.
// Tail (compaction, pair loop, reduce, plain store) identical to r6.
// ---------------------------------------------------------------------------
__global__ __launch_bounds__(1024, 4)
void triplet_row_kernel(const float* __restrict__ x,
                        const int* __restrict__ labels,
                        float* __restrict__ psum,
                        int* __restrict__ pcnt) {
    __shared__ float4 buf[F4P];       // 64 KB staging, XOR-swizzled rows
    __shared__ float drow[2][NPTS];   // distance rows for the 2 anchors
    __shared__ float posv[2][NPTS];
    __shared__ int   lab[NPTS];
    __shared__ int   npos_sh[2];
    __shared__ float wsum[16];
    __shared__ int   wcnt[16];

    const int tid = threadIdx.x;     // 0..1023
    const int h   = tid >> 9;        // half: 0 or 1
    const int t   = tid & 511;       // index within half
    const int w8  = t >> 6;          // wave-in-half 0..7
    const int l   = tid & 63;        // lane
    const int g   = l >> 2;          // row-group 0..15 within wave
    const int c   = l & 3;           // column slot 0..3

    const int i  = 2 * blockIdx.x + h;   // this half's anchor

    if (tid < NPTS) lab[tid] = labels[tid];
    if (tid < 2)    npos_sh[tid] = 0;
    const int li = labels[i];

    const float4* x4 = (const float4*)x;   // global as float4; row = idx>>5

    // anchor row fragment in registers (L1-broadcast, cheap)
    const float4* xi4 = (const float4*)(x + i * DIM);
    float4 xf[8];
#pragma unroll
    for (int it = 0; it < 8; ++it) xf[it] = xi4[c + 4 * it];

    float sqi = 0.f;
#pragma unroll
    for (int it = 0; it < 8; ++it) sqi += dot4(xf[it], xf[it]);
    sqi += __shfl_xor(sqi, 1, 64);
    sqi += __shfl_xor(sqi, 2, 64);

    // prologue: stage pass 0 (coalesced: lane-contiguous float4)
    {
        float4 stg[4];
#pragma unroll
        for (int u = 0; u < 4; ++u) stg[u] = x4[tid + 1024 * u];
#pragma unroll
        for (int u = 0; u < 4; ++u) {
            int v = tid + 1024 * u;
            int r = v >> 5, m = v & 31;
            buf[r * F4R + (m ^ (r & 7))] = stg[u];   // swizzled write
        }
    }

    for (int p = 0; p < 4; ++p) {
        __syncthreads();                 // staged pass-p writes visible

        // T14: issue next pass's global loads BEFORE computing pass p
        float4 nxt[4];
        if (p < 3) {
#pragma unroll
            for (int u = 0; u < 4; ++u)
                nxt[u] = x4[(p + 1) * F4P + tid + 1024 * u];
        }

        // compute pass p from LDS (both halves share the same buf)
        const int rl = w8 * 16 + g;      // local row 0..127
        const int j  = p * RPP + rl;
        const float4* brow = &buf[rl * F4R];
        float dp = 0.f, sp = 0.f;
#pragma unroll
        for (int it = 0; it < 8; ++it) {
            float4 b = brow[(c + 4 * it) ^ (rl & 7)];   // swizzled read
            dp += dot4(b, xf[it]);
            sp += dot4(b, b);
        }
        dp += __shfl_xor(dp, 1, 64);
        dp += __shfl_xor(dp, 2, 64);
        sp += __shfl_xor(sp, 1, 64);
        sp += __shfl_xor(sp, 2, 64);
        if (c == 0) {
            float dsq = sqi + sp - 2.f * dp;
            dsq = dsq > 0.f ? dsq : 0.f;
            // reference's zero-mask only affects exact-zero entries (the
            // diagonal), excluded by validity -> plain sqrt exact here.
            drow[h][j] = (dsq == 0.f) ? 0.f : sqrtf(dsq);
        }

        if (p < 3) {
            __syncthreads();             // all reads of buf done
#pragma unroll
            for (int u = 0; u < 4; ++u) {
                int v = tid + 1024 * u;
                int r = v >> 5, m = v & 31;
                buf[r * F4R + (m ^ (r & 7))] = nxt[u];
            }
        }
    }
    __syncthreads();

    // compact positives: one thread per row per half (~8 atomics/half)
    if (lab[t] == li && t != i) {
        int p = atomicAdd(&npos_sh[h], 1);
        posv[h][p] = drow[h][t] + MARGIN;
    }
    __syncthreads();
    const int npos = npos_sh[h];

    // pair loop: this thread owns k = t within its half
    const bool  isneg = (lab[t] != li);
    const float dk    = drow[h][t];
    float lsum = 0.f;
    int   lcnt = 0;
    for (int p = 0; p < npos; ++p) {
        float v = posv[h][p] - dk;       // d_ij - d_ik + margin
        if (isneg && v > 0.f) {
            lsum += v;
            lcnt += (v > CNT_EPS) ? 1 : 0;
        }
    }

    // per-wave shuffle reduce, then 16-partial combine (both anchors summed)
#pragma unroll
    for (int off = 1; off < 64; off <<= 1) {
        lsum += __shfl_xor(lsum, off, 64);
        lcnt += __shfl_xor(lcnt, off, 64);
    }
    const int wid = tid >> 6;            // 0..15
    if (l == 0) { wsum[wid] = lsum; wcnt[wid] = lcnt; }
    __syncthreads();
    if (tid == 0) {
        float s = 0.f;
        int   cc = 0;
#pragma unroll
        for (int q = 0; q < 16; ++q) { s += wsum[q]; cc += wcnt[q]; }
        psum[blockIdx.x] = s;            // plain stores; kernel-boundary
        pcnt[blockIdx.x] = cc;           // coherence is runtime-managed
    }
}

// ---------------------------------------------------------------------------
// Finalize: ONE wave, one float4/int4 per lane, shuffle reduce, no LDS.
// ---------------------------------------------------------------------------
__global__ void finalize_kernel(const float4* __restrict__ psum4,
                                const int4* __restrict__ pcnt4,
                                float* __restrict__ out) {
    const int t = threadIdx.x;           // 0..63 ; 64*4 = 256 partials
    float4 a  = psum4[t];
    int4   ca = pcnt4[t];
    float s  = a.x + a.y + a.z + a.w;
    int   cc = ca.x + ca.y + ca.z + ca.w;
#pragma unroll
    for (int off = 1; off < 64; off <<= 1) {
        s  += __shfl_xor(s, off, 64);
        cc += __shfl_xor(cc, off, 64);
    }
    if (t == 0) out[0] = s / (float)cc;
}

extern "C" void kernel_launch(void* const* d_in, const int* in_sizes, int n_in,
                              void* d_out, int out_size, void* d_ws, size_t ws_size,
                              hipStream_t stream) {
    const float* x      = (const float*)d_in[0];   // [512,128] fp32
    const int*   labels = (const int*)d_in[1];     // [512] int32
    float*       out    = (float*)d_out;           // scalar fp32

    float* psum = (float*)d_ws;          // 256 floats (fully overwritten)
    int*   pcnt = (int*)(psum + NBLK);   // 256 ints  (fully overwritten)

    triplet_row_kernel<<<NBLK, 1024, 0, stream>>>(x, labels, psum, pcnt);
    finalize_kernel<<<1, 64, 0, stream>>>((const float4*)psum,
                                          (const int4*)pcnt, out);
}

// Round 9
// 15.084 us; speedup vs baseline: 3.3193x; 1.9104x over previous
//
#include <hip/hip_runtime.h>

#define NPTS 512
#define DIM  128
#define MARGIN 0.5f
#define CNT_EPS 1e-8f
#define NBLK 256            // 2 anchors per block, 1 block per CU

__device__ __forceinline__ float dot4(float4 a, float4 b) {
    return a.x * b.x + a.y * b.y + a.z * b.z + a.w * b.w;
}

// ---------------------------------------------------------------------------
// One block (512 thr = 8 waves) per 2 anchors, grid 256 = 1 block/CU.
// KEY vs r6: each THREAD holds BOTH anchors' fragments (xf0, xf1), so one
// b-row load feeds dp0, dp1 and sp -> per-CU L1-pipe traffic halves
// (each xj row crosses the L1 pipe once per CU instead of twice).
// No LDS staging, no extra barriers (r8's failure mode).
// __launch_bounds__(512,2): 2 waves/SIMD, VGPR cap 256 -> no spill.
// Tail: single-step compaction + pair loop per anchor, shuffle reduce,
// plain global store; 64-thread finalize kernel (proven r5/r6 shape).
// ---------------------------------------------------------------------------
__global__ __launch_bounds__(512, 2)
void triplet_row_kernel(const float* __restrict__ x,
                        const int* __restrict__ labels,
                        float* __restrict__ psum,
                        int* __restrict__ pcnt) {
    __shared__ float drow[2][NPTS];   // distance rows for the 2 anchors
    __shared__ float posv[2][NPTS];
    __shared__ int   lab[NPTS];
    __shared__ int   npos_sh[2];
    __shared__ float wsum[8];
    __shared__ int   wcnt[8];

    const int tid = threadIdx.x;     // 0..511
    const int w   = tid >> 6;        // wave 0..7
    const int l   = tid & 63;        // lane
    const int g   = l >> 2;          // row-group 0..15 within wave
    const int c   = l & 3;           // column slot 0..3

    const int i0 = 2 * blockIdx.x;
    const int i1 = i0 + 1;

    lab[tid] = labels[tid];
    if (tid < 2) npos_sh[tid] = 0;
    const int li0 = labels[i0];
    const int li1 = labels[i1];

    // both anchors' row fragments in registers: columns c+4*it (it=0..7)
    const float4* xi0 = (const float4*)(x + i0 * DIM);
    const float4* xi1 = (const float4*)(x + i1 * DIM);
    float4 xf0[8], xf1[8];
#pragma unroll
    for (int it = 0; it < 8; ++it) xf0[it] = xi0[c + 4 * it];
#pragma unroll
    for (int it = 0; it < 8; ++it) xf1[it] = xi1[c + 4 * it];

    // squared norms of both anchors: per-lane partial, 4-lane butterfly
    float sq0 = 0.f, sq1 = 0.f;
#pragma unroll
    for (int it = 0; it < 8; ++it) {
        sq0 += dot4(xf0[it], xf0[it]);
        sq1 += dot4(xf1[it], xf1[it]);
    }
    sq0 += __shfl_xor(sq0, 1, 64);
    sq0 += __shfl_xor(sq0, 2, 64);
    sq1 += __shfl_xor(sq1, 1, 64);
    sq1 += __shfl_xor(sq1, 2, 64);

    // distance rows: pass p covers rows p*128 + w*16 + g; ONE b-load feeds
    // dp0, dp1, sp (the L1-traffic halving).
#pragma unroll 2
    for (int pass = 0; pass < 4; ++pass) {
        const int j = pass * 128 + w * 16 + g;
        const float4* xj4 = (const float4*)(x + j * DIM);
        float dp0 = 0.f, dp1 = 0.f, sp = 0.f;
#pragma unroll
        for (int it = 0; it < 8; ++it) {
            float4 b = xj4[c + 4 * it];
            dp0 += dot4(b, xf0[it]);
            dp1 += dot4(b, xf1[it]);
            sp  += dot4(b, b);
        }
        dp0 += __shfl_xor(dp0, 1, 64);
        dp0 += __shfl_xor(dp0, 2, 64);
        dp1 += __shfl_xor(dp1, 1, 64);
        dp1 += __shfl_xor(dp1, 2, 64);
        sp  += __shfl_xor(sp, 1, 64);
        sp  += __shfl_xor(sp, 2, 64);
        if (c == 0) {
            float dsq0 = sq0 + sp - 2.f * dp0;
            float dsq1 = sq1 + sp - 2.f * dp1;
            dsq0 = dsq0 > 0.f ? dsq0 : 0.f;
            dsq1 = dsq1 > 0.f ? dsq1 : 0.f;
            // reference's zero-mask only affects exact-zero entries (the
            // diagonal), excluded by validity -> plain sqrt exact here.
            drow[0][j] = (dsq0 == 0.f) ? 0.f : sqrtf(dsq0);
            drow[1][j] = (dsq1 == 0.f) ? 0.f : sqrtf(dsq1);
        }
    }
    __syncthreads();

    // compact positives: one thread per row per anchor (~8 atomics each)
    if (lab[tid] == li0 && tid != i0) {
        int p = atomicAdd(&npos_sh[0], 1);
        posv[0][p] = drow[0][tid] + MARGIN;
    }
    if (lab[tid] == li1 && tid != i1) {
        int p = atomicAdd(&npos_sh[1], 1);
        posv[1][p] = drow[1][tid] + MARGIN;
    }
    __syncthreads();
    const int npos0 = npos_sh[0];
    const int npos1 = npos_sh[1];

    // pair loops: this thread owns k = tid for both anchors
    float lsum = 0.f;
    int   lcnt = 0;
    {
        const bool  isneg = (lab[tid] != li0);
        const float dk    = drow[0][tid];
        for (int p = 0; p < npos0; ++p) {
            float v = posv[0][p] - dk;       // d_ij - d_ik + margin
            if (isneg && v > 0.f) {
                lsum += v;
                lcnt += (v > CNT_EPS) ? 1 : 0;
            }
        }
    }
    {
        const bool  isneg = (lab[tid] != li1);
        const float dk    = drow[1][tid];
        for (int p = 0; p < npos1; ++p) {
            float v = posv[1][p] - dk;
            if (isneg && v > 0.f) {
                lsum += v;
                lcnt += (v > CNT_EPS) ? 1 : 0;
            }
        }
    }

    // per-wave shuffle reduce, then 8-partial combine (both anchors summed)
#pragma unroll
    for (int off = 1; off < 64; off <<= 1) {
        lsum += __shfl_xor(lsum, off, 64);
        lcnt += __shfl_xor(lcnt, off, 64);
    }
    if (l == 0) { wsum[w] = lsum; wcnt[w] = lcnt; }
    __syncthreads();
    if (tid == 0) {
        float s = 0.f;
        int   cc = 0;
#pragma unroll
        for (int q = 0; q < 8; ++q) { s += wsum[q]; cc += wcnt[q]; }
        psum[blockIdx.x] = s;            // plain stores; kernel-boundary
        pcnt[blockIdx.x] = cc;           // coherence is runtime-managed
    }
}

// ---------------------------------------------------------------------------
// Finalize: ONE wave, one float4/int4 per lane, shuffle reduce, no LDS.
// ---------------------------------------------------------------------------
__global__ void finalize_kernel(const float4* __restrict__ psum4,
                                const int4* __restrict__ pcnt4,
                                float* __restrict__ out) {
    const int t = threadIdx.x;           // 0..63 ; 64*4 = 256 partials
    float4 a  = psum4[t];
    int4   ca = pcnt4[t];
    float s  = a.x + a.y + a.z + a.w;
    int   cc = ca.x + ca.y + ca.z + ca.w;
#pragma unroll
    for (int off = 1; off < 64; off <<= 1) {
        s  += __shfl_xor(s, off, 64);
        cc += __shfl_xor(cc, off, 64);
    }
    if (t == 0) out[0] = s / (float)cc;
}

extern "C" void kernel_launch(void* const* d_in, const int* in_sizes, int n_in,
                              void* d_out, int out_size, void* d_ws, size_t ws_size,
                              hipStream_t stream) {
    const float* x      = (const float*)d_in[0];   // [512,128] fp32
    const int*   labels = (const int*)d_in[1];     // [512] int32
    float*       out    = (float*)d_out;           // scalar fp32

    float* psum = (float*)d_ws;          // 256 floats (fully overwritten)
    int*   pcnt = (int*)(psum + NBLK);   // 256 ints  (fully overwritten)

    triplet_row_kernel<<<NBLK, 512, 0, stream>>>(x, labels, psum, pcnt);
    finalize_kernel<<<1, 64, 0, stream>>>((const float4*)psum,
                                          (const int4*)pcnt, out);
}

// Round 10
// 14.285 us; speedup vs baseline: 3.5049x; 1.0559x over previous
//
#include <hip/hip_runtime.h>

#define NPTS 512
#define DIM  128
#define MARGIN 0.5f
#define CNT_EPS 1e-8f
#define NBLK 256            // 2 anchors per block, 1 block per CU

__device__ __forceinline__ float dot4(float4 a, float4 b) {
    return a.x * b.x + a.y * b.y + a.z * b.z + a.w * b.w;
}

// ---------------------------------------------------------------------------
// One block (1024 thr = 16 waves) per 2 anchors, grid 256 = 1 block/CU
// -> 4 waves/SIMD (vs r9's 2) for L2-latency hiding, while KEEPING r9's
// one-load-feeds-both-anchors register sharing (per-CU traffic floor).
// Fit under 128 VGPR by widening to 8 lanes per row: per-anchor fragment
// is 4 float4, both anchors = 32 VGPR of fragments.
// Distance phase: 8 lanes/row, 8 rows/wave, 16 waves -> 128 rows/pass, 4 passes.
// Tail: r6-proven shape (half-per-anchor compaction + pair loop, wave
// shuffle reduce, 16-partial combine, plain store; 64-thread finalize).
// ---------------------------------------------------------------------------
__global__ __launch_bounds__(1024, 4)
void triplet_row_kernel(const float* __restrict__ x,
                        const int* __restrict__ labels,
                        float* __restrict__ psum,
                        int* __restrict__ pcnt) {
    __shared__ float drow[2][NPTS];   // distance rows for the 2 anchors
    __shared__ float posv[2][NPTS];
    __shared__ int   lab[NPTS];
    __shared__ int   npos_sh[2];
    __shared__ float wsum[16];
    __shared__ int   wcnt[16];

    const int tid = threadIdx.x;     // 0..1023
    const int w   = tid >> 6;        // wave 0..15
    const int l   = tid & 63;        // lane
    const int g   = l >> 3;          // row-group 0..7 within wave
    const int c   = l & 7;           // column slot 0..7 within group

    const int i0 = 2 * blockIdx.x;
    const int i1 = i0 + 1;

    if (tid < NPTS) lab[tid] = labels[tid];
    if (tid < 2)    npos_sh[tid] = 0;
    const int li0 = labels[i0];
    const int li1 = labels[i1];

    // both anchors' fragments in registers: columns c+8*it (it=0..3)
    const float4* xi0 = (const float4*)(x + i0 * DIM);
    const float4* xi1 = (const float4*)(x + i1 * DIM);
    float4 xf0[4], xf1[4];
#pragma unroll
    for (int it = 0; it < 4; ++it) xf0[it] = xi0[c + 8 * it];
#pragma unroll
    for (int it = 0; it < 4; ++it) xf1[it] = xi1[c + 8 * it];

    // squared norms: per-lane partial, 8-lane butterfly
    float sq0 = 0.f, sq1 = 0.f;
#pragma unroll
    for (int it = 0; it < 4; ++it) {
        sq0 += dot4(xf0[it], xf0[it]);
        sq1 += dot4(xf1[it], xf1[it]);
    }
    sq0 += __shfl_xor(sq0, 1, 64);
    sq0 += __shfl_xor(sq0, 2, 64);
    sq0 += __shfl_xor(sq0, 4, 64);
    sq1 += __shfl_xor(sq1, 1, 64);
    sq1 += __shfl_xor(sq1, 2, 64);
    sq1 += __shfl_xor(sq1, 4, 64);

    // distance rows: pass p covers rows p*128 + w*8 + g; ONE b-load feeds
    // dp0, dp1 and sp (register-level sharing, per-CU traffic at floor).
#pragma unroll 2
    for (int pass = 0; pass < 4; ++pass) {
        const int j = pass * 128 + w * 8 + g;
        const float4* xj4 = (const float4*)(x + j * DIM);
        float dp0 = 0.f, dp1 = 0.f, sp = 0.f;
#pragma unroll
        for (int it = 0; it < 4; ++it) {
            float4 b = xj4[c + 8 * it];
            dp0 += dot4(b, xf0[it]);
            dp1 += dot4(b, xf1[it]);
            sp  += dot4(b, b);
        }
        dp0 += __shfl_xor(dp0, 1, 64);
        dp0 += __shfl_xor(dp0, 2, 64);
        dp0 += __shfl_xor(dp0, 4, 64);
        dp1 += __shfl_xor(dp1, 1, 64);
        dp1 += __shfl_xor(dp1, 2, 64);
        dp1 += __shfl_xor(dp1, 4, 64);
        sp  += __shfl_xor(sp, 1, 64);
        sp  += __shfl_xor(sp, 2, 64);
        sp  += __shfl_xor(sp, 4, 64);
        if (c == 0) {
            float dsq0 = sq0 + sp - 2.f * dp0;
            float dsq1 = sq1 + sp - 2.f * dp1;
            dsq0 = dsq0 > 0.f ? dsq0 : 0.f;
            dsq1 = dsq1 > 0.f ? dsq1 : 0.f;
            // reference's zero-mask only affects exact-zero entries (the
            // diagonal), excluded by validity -> plain sqrt exact here.
            drow[0][j] = (dsq0 == 0.f) ? 0.f : sqrtf(dsq0);
            drow[1][j] = (dsq1 == 0.f) ? 0.f : sqrtf(dsq1);
        }
    }
    __syncthreads();

    // compaction + pair loop: half h owns anchor i_h, thread handles k=t
    const int h = tid >> 9;          // 0 or 1
    const int t = tid & 511;
    const int lih = h ? li1 : li0;
    const int ih  = h ? i1 : i0;

    if (lab[t] == lih && t != ih) {
        int p = atomicAdd(&npos_sh[h], 1);
        posv[h][p] = drow[h][t] + MARGIN;
    }
    __syncthreads();
    const int npos = npos_sh[h];

    const bool  isneg = (lab[t] != lih);
    const float dk    = drow[h][t];
    float lsum = 0.f;
    int   lcnt = 0;
    for (int p = 0; p < npos; ++p) {
        float v = posv[h][p] - dk;       // d_ij - d_ik + margin
        if (isneg && v > 0.f) {
            lsum += v;
            lcnt += (v > CNT_EPS) ? 1 : 0;
        }
    }

    // per-wave shuffle reduce, then 16-partial combine (both anchors summed)
#pragma unroll
    for (int off = 1; off < 64; off <<= 1) {
        lsum += __shfl_xor(lsum, off, 64);
        lcnt += __shfl_xor(lcnt, off, 64);
    }
    if (l == 0) { wsum[w] = lsum; wcnt[w] = lcnt; }
    __syncthreads();
    if (tid == 0) {
        float s = 0.f;
        int   cc = 0;
#pragma unroll
        for (int q = 0; q < 16; ++q) { s += wsum[q]; cc += wcnt[q]; }
        psum[blockIdx.x] = s;            // plain stores; kernel-boundary
        pcnt[blockIdx.x] = cc;           // coherence is runtime-managed
    }
}

// ---------------------------------------------------------------------------
// Finalize: ONE wave, one float4/int4 per lane, shuffle reduce, no LDS.
// ---------------------------------------------------------------------------
__global__ void finalize_kernel(const float4* __restrict__ psum4,
                                const int4* __restrict__ pcnt4,
                                float* __restrict__ out) {
    const int t = threadIdx.x;           // 0..63 ; 64*4 = 256 partials
    float4 a  = psum4[t];
    int4   ca = pcnt4[t];
    float s  = a.x + a.y + a.z + a.w;
    int   cc = ca.x + ca.y + ca.z + ca.w;
#pragma unroll
    for (int off = 1; off < 64; off <<= 1) {
        s  += __shfl_xor(s, off, 64);
        cc += __shfl_xor(cc, off, 64);
    }
    if (t == 0) out[0] = s / (float)cc;
}

extern "C" void kernel_launch(void* const* d_in, const int* in_sizes, int n_in,
                              void* d_out, int out_size, void* d_ws, size_t ws_size,
                              hipStream_t stream) {
    const float* x      = (const float*)d_in[0];   // [512,128] fp32
    const int*   labels = (const int*)d_in[1];     // [512] int32
    float*       out    = (float*)d_out;           // scalar fp32

    float* psum = (float*)d_ws;          // 256 floats (fully overwritten)
    int*   pcnt = (int*)(psum + NBLK);   // 256 ints  (fully overwritten)

    triplet_row_kernel<<<NBLK, 1024, 0, stream>>>(x, labels, psum, pcnt);
    finalize_kernel<<<1, 64, 0, stream>>>((const float4*)psum,
                                          (const int4*)pcnt, out);
}